// Round 7
// baseline (905.082 us; speedup 1.0000x reference)
//
#include <hip/hip_runtime.h>
#include <stdint.h>

typedef short v8s __attribute__((ext_vector_type(8)));
typedef short v4s __attribute__((ext_vector_type(4)));
typedef float v4f __attribute__((ext_vector_type(4)));

#define BM 256         // rows per block
#define BN 256         // cols per block (NT = 1024/256 = 4)
#define BKH 32         // shorts per row per k-step (64 B rows -- proven swizzle unit)
#define ASH (BM * BKH)          // A region shorts per buffer (16 KB)
#define TSH ((BM + BN) * BKH)   // shorts per buffer = 16384 (32 KB); x2 = 64 KB
#define POS_INF __builtin_inff()

typedef __attribute__((address_space(3))) unsigned int lds_uint;
typedef const __attribute__((address_space(1))) unsigned int glb_uint;

__device__ __forceinline__ void load16_lds(const void* g, void* l) {
    // 16B per lane, LDS dest = wave-uniform base + lane*16
    __builtin_amdgcn_global_load_lds((glb_uint*)g, (lds_uint*)l, 16, 0, 0);
}

__device__ __forceinline__ short f2bf(float f) {
    uint32_t u = __builtin_bit_cast(uint32_t, f);
    u += 0x7fffu + ((u >> 16) & 1u);
    return (short)(u >> 16);
}

// Fused prep (restored from the verified 283us kernel): blocks [0, CB)
// normalize centers (1 row per wave) and pad rows [C, CP) with zeros, plus
// zero the rowblock counters and d_out; blocks [CB, ...) convert x
// fp32->bf16 at pure memory BW. (R6 proved deleting this pass costs more
// in-GEMM than it saves: fp32 A doubles LDS/L2 traffic and 128-B rows
// cannot be bank-conflict-free -- row offset vanishes mod 32 banks.)
__global__ void prep(const float* __restrict__ centers,
                     unsigned short* __restrict__ cbf,
                     int C, int D, int CP, int CB,
                     const float* __restrict__ x,
                     unsigned short* __restrict__ xbf, size_t nx,
                     int* __restrict__ cnt, int NB,
                     float* __restrict__ out) {
    const int b = blockIdx.x;
    const int t = threadIdx.x;
    if (b == 0 && t == 0) out[0] = 0.0f;
    if (b < CB) {
        const int g = b * 256 + t;
        if (g < NB) cnt[g] = 0;
        const int wave = t >> 6, lane = t & 63;
        const int row = b * 4 + wave;
        if (row >= CP) return;
        if (row >= C) {
            v4s z = {0, 0, 0, 0};
            for (int d = lane * 4; d < D; d += 256)
                *(v4s*)&cbf[(size_t)row * D + d] = z;
            return;
        }
        const float* src = centers + (size_t)row * D;
        float ss = 0.0f;
        for (int d = lane * 4; d < D; d += 256) {
            v4f f = *(const v4f*)&src[d];
            ss += f.x * f.x + f.y * f.y + f.z * f.z + f.w * f.w;
        }
        #pragma unroll
        for (int off = 32; off; off >>= 1) ss += __shfl_xor(ss, off, 64);
        const float rn = rsqrtf(ss);
        for (int d = lane * 4; d < D; d += 256) {
            v4f f = *(const v4f*)&src[d];
            v4s s;
            s.x = f2bf(f.x * rn); s.y = f2bf(f.y * rn);
            s.z = f2bf(f.z * rn); s.w = f2bf(f.w * rn);
            *(v4s*)&cbf[(size_t)row * D + d] = s;
        }
    } else {
        const size_t i = ((size_t)(b - CB) * 256 + t) * 8;
        if (i >= nx) return;
        v4f f0 = *(const v4f*)&x[i];
        v4f f1 = *(const v4f*)&x[i + 4];
        v8s s;
        s[0] = f2bf(f0.x); s[1] = f2bf(f0.y); s[2] = f2bf(f0.z); s[3] = f2bf(f0.w);
        s[4] = f2bf(f1.x); s[5] = f2bf(f1.y); s[6] = f2bf(f1.z); s[7] = f2bf(f1.w);
        *(v8s*)&xbf[i] = s;
    }
}

// Fused GEMM + row-min epilogue + last-block finisher.
// R7: WIDER BLOCK, identical per-wave geometry. 256x256 tile, 1024 threads
// = 16 waves (4x4 wave grid, 64x64/wave). Each wave's k-step is
// bit-identical to R4's (8 ds_read_b128 + 16 MFMA, same proven-zero
// swizzle, same ~64 VGPR), but A and B are now each shared 4-way across
// waves: staging traffic per FLOP HALVES (32 KB per 2M MACs vs R4's 24 KB
// per 1M), DMA drops to 2 instrs/wave/step, and xbf's L2/L3 re-read
// halves (NT 8 -> 4). LDS 2 x 32 KB = 64 KB; __launch_bounds__(1024, 8)
// pins VGPR <= 64 so 2 blocks/CU = 32 waves/CU -- the most TLP of any
// variant (ledger: TLP is the only axis that has ever mattered here).
// Sync = R6's 2-buffer WAITVM0 -> s_barrier -> STAGE(next) -> TILE(cur):
// each DMA group gets a full compute phase to land; R4 proved the counted
// 3-buffer variant is worth ~3 us, not worth losing a resident block.
//
// Swizzle (proven 0-conflict, R4/R0): 64-B rows; slot chunk s of row r
// holds source chunk s ^ ((r>>1)&3); DMA source permute csrc =
// (lane&3) ^ ((lane>>3)&3), rsub = lane>>2; read slot q ^ ((l15>>1)&3).
// MFMA accumulation stays global-k-ascending -> bit-identical numerics.
//
// Cross-block protocol unchanged: NO acquire/release fences (agent-scope
// ACQ_REL RMW emits buffer_inv/buffer_wbl2 = per-XCD L2 flush; measured
// +59% k-loop time). pos/partial use RELAXED agent-scope atomics;
// __syncthreads drains vmcnt(0) before the RELAXED counter RMW; RMW total
// order + control dependency orders the finisher's relaxed loads.
__global__ void __launch_bounds__(1024, 8)
gemm_fused(const unsigned short* __restrict__ xbf,
           const unsigned short* __restrict__ cbf,
           const int* __restrict__ labels,
           float* __restrict__ pos, float* __restrict__ partial,
           int* __restrict__ cnt,
           int Bt, int C, int D, int NT, float margin,
           float* __restrict__ out) {
    extern __shared__ short LDS[];   // 2 * TSH shorts = 64 KB

    const int t   = threadIdx.x;
    const int bid = blockIdx.x;
    const int xcd = bid & 7;
    const int per = bid >> 3;
    const int rowblk = (per >> 2) * 8 + xcd;   // NT=4: a rowblock's 4
    const int nt     = per & 3;                // n-tiles consecutive per XCD
    const int row0 = rowblk * BM;
    const int n0   = nt * BN;

    const int lane = t & 63;
    const int wave = t >> 6;          // 0..15
    const int wm = wave >> 2;         // 0..3 -> m offset wm*64
    const int wn = wave & 3;          // 0..3 -> n offset wn*64
    const int l15 = lane & 15, q = lane >> 4;

    // staging lane decomposition: 16 rows x 4 chunks per DMA instruction
    const int rsub = lane >> 2;                       // row within 16-row group
    const int csrc = (lane & 3) ^ ((lane >> 3) & 3);  // g(r) = (r>>1)&3

    // prefetch this thread's label (oldest vm op; retired by first WAITVM0)
    int myLab = 0;
    if (t < BM) myLab = labels[row0 + t];

    v4f acc[4][4];
    #pragma unroll
    for (int i = 0; i < 4; ++i)
        #pragma unroll
        for (int j = 0; j < 4; ++j)
            acc[i][j] = (v4f){0.f, 0.f, 0.f, 0.f};

    #define WAITVM0() do { asm volatile("s_waitcnt vmcnt(0)" ::: "memory"); } while (0)
    #define BARRIER() do { __builtin_amdgcn_s_barrier(); \
                           __builtin_amdgcn_sched_barrier(0); } while (0)

    // stage one 32 KB k-step tile (A 16 KB + B 16 KB): 2 DMA instrs/wave
    #define STAGE(buf_, k0_) do {                                            \
        load16_lds(&xbf[(size_t)(row0 + wave * 16 + rsub) * D + (k0_) + csrc * 8], \
                   &LDS[(buf_) + (wave * 16) * BKH]);                        \
        load16_lds(&cbf[(size_t)(n0 + wave * 16 + rsub) * D + (k0_) + csrc * 8], \
                   &LDS[(buf_) + ASH + (wave * 16) * BKH]);                  \
    } while (0)

    // one k-step: 8 ds_read_b128 + 16 MFMA; read slot = q ^ ((l15>>1)&3)
    #define TILE(buf_) do {                                                  \
        v8s a[4], b[4];                                                      \
        _Pragma("unroll")                                                    \
        for (int i = 0; i < 4; ++i)                                          \
            a[i] = *(const v8s*)&LDS[(buf_) + (wm * 64 + i * 16 + l15) * BKH \
                                     + ((q ^ ((l15 >> 1) & 3)) << 3)];       \
        _Pragma("unroll")                                                    \
        for (int j = 0; j < 4; ++j)                                          \
            b[j] = *(const v8s*)&LDS[(buf_) + ASH + (wn * 64 + j * 16 + l15) * BKH \
                                     + ((q ^ ((l15 >> 1) & 3)) << 3)];       \
        _Pragma("unroll")                                                    \
        for (int i = 0; i < 4; ++i)                                          \
            _Pragma("unroll")                                                \
            for (int j = 0; j < 4; ++j)                                      \
                acc[i][j] = __builtin_amdgcn_mfma_f32_16x16x32_bf16(         \
                    a[i], b[j], acc[i][j], 0, 0, 0);                         \
    } while (0)

    int bc = 0, bnx = TSH;           // rotating buffer offsets (short units)

    STAGE(bc, 0);                    // prologue: tile 0 in flight

    const int KT = D / BKH;          // 16
    for (int kt = 0; kt < KT; ++kt) {
        WAITVM0();                   // my stage(kt) landed (issued a full
                                     // compute phase ago; residual wait)
        BARRIER();                   // everyone's stage(kt) visible; all
                                     // waves done with buf[kt-1] -> WAR ok
        if (kt + 1 < KT) STAGE(bnx, (kt + 1) * BKH);
        TILE(bc);
        const int tmp = bc; bc = bnx; bnx = tmp;
    }

    #undef STAGE
    #undef TILE
    #undef WAITVM0
    #undef BARRIER

    __syncthreads();   // all reads done before LDS reuse; drains counters

    // ---- Epilogue (k-loop LDS dead; alias scratch) ----
    int*   Ls    = (int*)LDS;                     // [BM] labels (1 KB)
    float* sMinW = (float*)((char*)LDS + 1024);   // [4*BM] (4 KB)
    int*   sLast = (int*)((char*)LDS + 5120);
    float* wsum  = (float*)((char*)LDS + 5136);   // 16 floats
    if (t < BM) Ls[t] = myLab;
    __syncthreads();

    // dist = 1 - acc; stash pos at label col; row-min over valid cols.
    // C/D layout (16x16x32): col = lane&15, row = q*4 + reg
    #pragma unroll
    for (int i = 0; i < 4; ++i) {
        #pragma unroll
        for (int rg = 0; rg < 4; ++rg) {
            const int row_l = wm * 64 + i * 16 + q * 4 + rg;
            const int lab = Ls[row_l];
            float m = POS_INF;
            #pragma unroll
            for (int j = 0; j < 4; ++j) {
                const int col = n0 + wn * 64 + j * 16 + l15;
                const float d = 1.0f - acc[i][j][rg];
                if (col == lab)
                    __hip_atomic_store(&pos[row0 + row_l], d,
                                       __ATOMIC_RELAXED, __HIP_MEMORY_SCOPE_AGENT);
                else if (col < C) m = fminf(m, d);
            }
            m = fminf(m, __shfl_xor(m, 1, 64));
            m = fminf(m, __shfl_xor(m, 2, 64));
            m = fminf(m, __shfl_xor(m, 4, 64));
            m = fminf(m, __shfl_xor(m, 8, 64));
            if (l15 == 0) sMinW[wn * BM + row_l] = m;
        }
    }
    __syncthreads();
    if (t < BM) {
        const float m = fminf(fminf(sMinW[t], sMinW[BM + t]),
                              fminf(sMinW[2 * BM + t], sMinW[3 * BM + t]));
        __hip_atomic_store(&partial[(size_t)nt * Bt + row0 + t], m,
                           __ATOMIC_RELAXED, __HIP_MEMORY_SCOPE_AGENT);
    }
    __syncthreads();  // drains vmcnt(0): all stores at coherence point

    // Completion counter: RELAXED on purpose (no buffer_inv/buffer_wbl2).
    if (t == 0) {
        __builtin_amdgcn_s_waitcnt(0);  // belt-and-braces; already drained
        const int old = __hip_atomic_fetch_add(&cnt[rowblk], 1,
                                               __ATOMIC_RELAXED,
                                               __HIP_MEMORY_SCOPE_AGENT);
        *sLast = (old == NT - 1);
    }
    __syncthreads();
    if (!*sLast) return;

    float hng = 0.0f;
    if (t < BM) {
        const int r = row0 + t;
        float neg = POS_INF;
        for (int tt = 0; tt < NT; ++tt)
            neg = fminf(neg, __hip_atomic_load(&partial[(size_t)tt * Bt + r],
                                               __ATOMIC_RELAXED,
                                               __HIP_MEMORY_SCOPE_AGENT));
        const float p = __hip_atomic_load(&pos[r], __ATOMIC_RELAXED,
                                          __HIP_MEMORY_SCOPE_AGENT);
        hng = fmaxf(0.0f, p + margin - neg);
    }
    #pragma unroll
    for (int off = 32; off; off >>= 1) hng += __shfl_down(hng, off, 64);
    if (lane == 0) wsum[wave] = hng;
    __syncthreads();
    if (t == 0) {
        float s = 0.0f;
        #pragma unroll
        for (int w = 0; w < 16; ++w) s += wsum[w];
        atomicAdd(out, s * (1.0f / (float)Bt));
    }
}

extern "C" void kernel_launch(void* const* d_in, const int* in_sizes, int n_in,
                              void* d_out, int out_size, void* d_ws, size_t ws_size,
                              hipStream_t stream) {
    const float* x       = (const float*)d_in[0];
    const int*   labels  = (const int*)d_in[1];
    const float* centers = (const float*)d_in[2];
    float* out = (float*)d_out;

    const int Bt = in_sizes[1];           // 65536
    const int D  = in_sizes[0] / Bt;      // 512
    const int C  = in_sizes[2] / D;       // 1000
    const int NT = (C + BN - 1) / BN;     // 4
    const int CP = NT * BN;               // 1024
    const int NB = Bt / BM;               // 256 rowblocks

    char* ws = (char*)d_ws;
    unsigned short* cbf = (unsigned short*)ws;          // CP*D bf16 = 1 MB
    size_t off = (size_t)CP * D * 2;
    off = (off + 255) & ~(size_t)255;
    float* pos = (float*)(ws + off);      off += (size_t)Bt * 4;       // 256 KB
    float* partial = (float*)(ws + off);  off += (size_t)NT * Bt * 4;  // 1 MB
    int* cnt = (int*)(ws + off);          off += (size_t)NB * 4;
    off = (off + 255) & ~(size_t)255;
    unsigned short* xbf = (unsigned short*)(ws + off);   // 64 MB

    const size_t nx = (size_t)Bt * D;
    const int CB = CP / 4;                                // center blocks
    const int XB = (int)((nx / 8 + 255) / 256);           // convert blocks
    prep<<<CB + XB, 256, 0, stream>>>(centers, cbf, C, D, CP, CB, x, xbf, nx,
                                      cnt, NB, out);

    // 64 KB dynamic LDS: set the opt-in attribute (one-time, host-side,
    // not a stream op -> graph-capture safe).
    static bool lds_attr_set = false;
    if (!lds_attr_set) {
        hipFuncSetAttribute(reinterpret_cast<const void*>(gemm_fused),
                            hipFuncAttributeMaxDynamicSharedMemorySize,
                            2 * TSH * (int)sizeof(short));
        lds_attr_set = true;
    }
    gemm_fused<<<NB * NT, 1024, 2 * TSH * sizeof(short), stream>>>(
        xbf, cbf, labels, pos, partial, cnt, Bt, C, D, NT, 1.0f, out);
}

// Round 8
// 304.908 us; speedup vs baseline: 2.9684x; 2.9684x over previous
//
#include <hip/hip_runtime.h>
#include <stdint.h>

typedef short v8s __attribute__((ext_vector_type(8)));
typedef short v4s __attribute__((ext_vector_type(4)));
typedef float v4f __attribute__((ext_vector_type(4)));

#define BM 256         // rows per block
#define BN 256         // cols per block (NT = 1024/256 = 4)
#define BK 64          // shorts per row per k-tile (128 B)
#define ASH (BM * BK)              // 16384 shorts = 32 KB
#define BSH (BN * BK)              // 16384 shorts = 32 KB
#define BUFSH (ASH + BSH)          // 64 KB per buffer; x2 dbuf = 128 KB LDS
#define POS_INF __builtin_inff()

typedef __attribute__((address_space(3))) unsigned int lds_uint;
typedef const __attribute__((address_space(1))) unsigned int glb_uint;

__device__ __forceinline__ void load16_lds(const void* g, void* l) {
    // 16B per lane, LDS dest = wave-uniform base + lane*16
    __builtin_amdgcn_global_load_lds((glb_uint*)g, (lds_uint*)l, 16, 0, 0);
}

__device__ __forceinline__ short f2bf(float f) {
    uint32_t u = __builtin_bit_cast(uint32_t, f);
    u += 0x7fffu + ((u >> 16) & 1u);
    return (short)(u >> 16);
}

// Fused prep (unchanged from the verified 283us kernel): blocks [0, CB)
// normalize centers (1 row per wave) and pad rows [C, CP) with zeros, plus
// zero the rowblock counters and d_out; blocks [CB, ...) convert x
// fp32->bf16 at pure memory BW.
__global__ void prep(const float* __restrict__ centers,
                     unsigned short* __restrict__ cbf,
                     int C, int D, int CP, int CB,
                     const float* __restrict__ x,
                     unsigned short* __restrict__ xbf, size_t nx,
                     int* __restrict__ cnt, int NB,
                     float* __restrict__ out) {
    const int b = blockIdx.x;
    const int t = threadIdx.x;
    if (b == 0 && t == 0) out[0] = 0.0f;
    if (b < CB) {
        const int g = b * 256 + t;
        if (g < NB) cnt[g] = 0;
        const int wave = t >> 6, lane = t & 63;
        const int row = b * 4 + wave;
        if (row >= CP) return;
        if (row >= C) {
            v4s z = {0, 0, 0, 0};
            for (int d = lane * 4; d < D; d += 256)
                *(v4s*)&cbf[(size_t)row * D + d] = z;
            return;
        }
        const float* src = centers + (size_t)row * D;
        float ss = 0.0f;
        for (int d = lane * 4; d < D; d += 256) {
            v4f f = *(const v4f*)&src[d];
            ss += f.x * f.x + f.y * f.y + f.z * f.z + f.w * f.w;
        }
        #pragma unroll
        for (int off = 32; off; off >>= 1) ss += __shfl_xor(ss, off, 64);
        const float rn = rsqrtf(ss);
        for (int d = lane * 4; d < D; d += 256) {
            v4f f = *(const v4f*)&src[d];
            v4s s;
            s.x = f2bf(f.x * rn); s.y = f2bf(f.y * rn);
            s.z = f2bf(f.z * rn); s.w = f2bf(f.w * rn);
            *(v4s*)&cbf[(size_t)row * D + d] = s;
        }
    } else {
        const size_t i = ((size_t)(b - CB) * 256 + t) * 8;
        if (i >= nx) return;
        v4f f0 = *(const v4f*)&x[i];
        v4f f1 = *(const v4f*)&x[i + 4];
        v8s s;
        s[0] = f2bf(f0.x); s[1] = f2bf(f0.y); s[2] = f2bf(f0.z); s[3] = f2bf(f0.w);
        s[4] = f2bf(f1.x); s[5] = f2bf(f1.y); s[6] = f2bf(f1.z); s[7] = f2bf(f1.w);
        *(v8s*)&xbf[i] = s;
    }
}

// ---- 8-phase schedule helpers -------------------------------------------
// R8 vs R1 (123us): the ONLY change is removing every sched_barrier(0).
// R1 emitted 24+ compile-time scheduling fences per K-tile, pinning
// instruction order and forbidding the compiler from interleaving ds_read
// issue / DMA issue / MFMA within phases -- the m141 pathology (874->510
// TF from order-pinning). m201's verified template has ZERO sched
// fences: raw s_barrier separates phases; SSA dependencies make the
// compiler insert exact lgkmcnt waits before MFMA consumers. R1 passed
// correctness, so the barrier/wait SEMANTICS (placement and counts) are
// already proven; only the fences go.
#define BARRIER() __builtin_amdgcn_s_barrier()
// Counted vmcnt: keep prefetch DMA in flight across barriers (T4).
#define WAITVM(N) asm volatile("s_waitcnt vmcnt(" #N ")" ::: "memory")

// Per-wave staging. FIFO issue order per tile is FIXED: B0,B1,B2,B3,A0..A3.
// A-slot s covers rows {s*32..+32} U {128+s*32..+32} == exactly the A rows
// quadrant s's MFMAs read, so counted waits retire precisely what's needed.
// LDS invariant (proven 0-conflict): row r, slot chunk c holds source chunk
// c^(r&7); DMA writes base+lane*16 so the SOURCE address is permuted.
#define STAGE_A(dst, s, k0) \
    load16_lds(&xbf[gA + (size_t)(s) * 32 * D + (size_t)(k0)], \
               (dst) + ((s) * 32 + ((wave & 3) << 3) + ((wave >> 2) << 7)) * BK)
#define STAGE_B(dst, bslot, k0) \
    load16_lds(&cbf[gB + (size_t)(bslot) * 8 * D + (size_t)(k0)], \
               (dst) + (wave * 32 + (bslot) * 8) * BK)

#define LDS_A(Ac, p) do { \
    _Pragma("unroll") \
    for (int ii = 0; ii < 2; ++ii) { \
        const int m_ = wm * 128 + (2 * (p) + ii) * 16 + l15; \
        _Pragma("unroll") \
        for (int kh = 0; kh < 2; ++kh) \
            a[ii][kh] = *(const v8s*)&(Ac)[m_ * BK + ((((kh << 2) + q) ^ (l15 & 7)) << 3)]; \
    } } while (0)

#define LDS_B(Bc) do { \
    _Pragma("unroll") \
    for (int j = 0; j < 4; ++j) { \
        const int n_ = wn * 64 + j * 16 + l15; \
        _Pragma("unroll") \
        for (int kh = 0; kh < 2; ++kh) \
            b[j][kh] = *(const v8s*)&(Bc)[n_ * BK + ((((kh << 2) + q) ^ (l15 & 7)) << 3)]; \
    } } while (0)

// One C-quadrant x K=64 = 16 MFMA, setprio-wrapped (T5: pays on 8-phase).
// Accumulation order per acc element (kh=0 then 1, tiles in order) is
// identical to the verified kernels -> bitwise-identical numerics.
#define MFMA16(p) do { \
    __builtin_amdgcn_s_setprio(1); \
    _Pragma("unroll") \
    for (int ii = 0; ii < 2; ++ii) \
        _Pragma("unroll") \
        for (int j = 0; j < 4; ++j) \
            _Pragma("unroll") \
            for (int kh = 0; kh < 2; ++kh) \
                acc[2 * (p) + ii][j] = __builtin_amdgcn_mfma_f32_16x16x32_bf16( \
                    a[ii][kh], b[j][kh], acc[2 * (p) + ii][j], 0, 0, 0); \
    __builtin_amdgcn_s_setprio(0); \
} while (0)

// Fused GEMM + row-min epilogue + last-block-per-rowblock loss finisher.
// 256x256 tile, 512 threads = 8 waves (2M x 4N, 128x64 per wave): HALF the
// LDS bytes per FLOP of the 64x64-wave kernels (R4's 99us sits at the
// 64x64 LDS-BW floor; this geometry's floor is ~35-50us). 8-phase
// counted-vmcnt schedule, steady-state waits (5,7,8,3): in-flight DMA
// never below 3 until the tail. LDS 128 KB dbuf -> 1 block/CU.
// Correctness of waits/barriers proven by R1's passing run.
//
// Cross-block protocol unchanged: relaxed agent-scope atomics, no
// acquire/release fences (those flush per-XCD L2: measured +59% k-loop).
__global__ void __launch_bounds__(512, 2)
gemm_fused(const unsigned short* __restrict__ xbf,
           const unsigned short* __restrict__ cbf,
           const int* __restrict__ labels,
           float* __restrict__ pos, float* __restrict__ partial,
           int* __restrict__ cnt,
           int Bt, int C, int D, int NT, float margin,
           float* __restrict__ out) {
    extern __shared__ short LDS[];   // 2 * 64 KB

    const int t   = threadIdx.x;
    const int bid = blockIdx.x;
    const int xcd = bid & 7;
    const int per = bid >> 3;
    const int rowblk = (per >> 2) * 8 + xcd;   // NT=4: same rowblock's 4
    const int nt     = per & 3;                // n-tiles consecutive per XCD
    const int row0 = rowblk * BM;
    const int n0   = nt * BN;

    const int lane = t & 63;
    const int wave = t >> 6;          // 0..7
    const int wm = wave >> 2;         // 0..1 -> m offset wm*128
    const int wn = wave & 3;          // 0..3 -> n offset wn*64
    const int l15 = lane & 15, q = lane >> 4;
    const int rsub = lane >> 3;              // row within 8-row group
    const int csrc = (lane & 7) ^ rsub;      // swizzled source chunk

    int myLab = 0;
    if (t < BM) myLab = labels[row0 + t];

    // per-wave global staging bases (lane-resolved)
    const size_t gA = (size_t)(row0 + ((wave & 3) << 3) + ((wave >> 2) << 7) + rsub) * D + csrc * 8;
    const size_t gB = (size_t)(n0 + wave * 32 + rsub) * D + csrc * 8;

    v4f acc[8][4];
    #pragma unroll
    for (int i = 0; i < 8; ++i)
        #pragma unroll
        for (int j = 0; j < 4; ++j)
            acc[i][j] = (v4f){0.f, 0.f, 0.f, 0.f};

    const int KT = D / BK;            // 8
    v8s a[2][2], b[4][2];

    {   // prologue: tile 0 -> buf0. vmcnt(3) = B0-3 + A0 done (5 oldest of 8)
        short* An = LDS;  short* Bn = LDS + ASH;
        STAGE_B(Bn, 0, 0); STAGE_B(Bn, 1, 0); STAGE_B(Bn, 2, 0); STAGE_B(Bn, 3, 0);
        STAGE_A(An, 0, 0); STAGE_A(An, 1, 0); STAGE_A(An, 2, 0); STAGE_A(An, 3, 0);
        WAITVM(3);
        BARRIER();
    }

    for (int kt = 0; kt < KT - 1; ++kt) {
        short* Ac = LDS + (kt & 1) * BUFSH;        short* Bc = Ac + ASH;
        short* An = LDS + ((kt & 1) ^ 1) * BUFSH;  short* Bn = An + ASH;
        const int kn = (kt + 1) * BK;
        // ph0: needs B(all)+A0 (guaranteed by prev tile's vmcnt(3)+barrier)
        LDS_B(Bc); LDS_A(Ac, 0);
        STAGE_B(Bn, 0, kn); STAGE_B(Bn, 1, kn); STAGE_B(Bn, 2, kn);
        BARRIER(); MFMA16(0); WAITVM(5); BARRIER();   // retire A1
        // ph1
        LDS_A(Ac, 1);
        STAGE_B(Bn, 3, kn); STAGE_A(An, 0, kn); STAGE_A(An, 1, kn);
        BARRIER(); MFMA16(1); WAITVM(7); BARRIER();   // retire A2
        // ph2
        LDS_A(Ac, 2);
        STAGE_A(An, 2, kn); STAGE_A(An, 3, kn);
        BARRIER(); MFMA16(2); WAITVM(8); BARRIER();   // retire A3
        // ph3
        LDS_A(Ac, 3);
        BARRIER(); MFMA16(3); WAITVM(3); BARRIER();   // retire next B0-3+A0
    }
    {   // tail tile: no prefetch; drain {A1,A2,A3} with 2,1,0
        short* Ac = LDS + ((KT - 1) & 1) * BUFSH;  short* Bc = Ac + ASH;
        LDS_B(Bc); LDS_A(Ac, 0);
        BARRIER(); MFMA16(0); WAITVM(2); BARRIER();
        LDS_A(Ac, 1);
        BARRIER(); MFMA16(1); WAITVM(1); BARRIER();
        LDS_A(Ac, 2);
        BARRIER(); MFMA16(2); WAITVM(0); BARRIER();
        LDS_A(Ac, 3);
        BARRIER(); MFMA16(3);
    }
    __syncthreads();   // full drain before LDS reuse

    // ---- Epilogue (k-loop LDS dead; alias scratch) ----
    int*   Ls    = (int*)LDS;                     // [256] labels, 1 KB
    float* sMinW = (float*)((char*)LDS + 1024);   // [4][256] = 4 KB
    int*   sLast = (int*)((char*)LDS + 5120);
    float* wsum  = (float*)((char*)LDS + 5136);   // 8 floats
    if (t < BM) Ls[t] = myLab;
    __syncthreads();

    // dist = 1 - acc; stash pos at label col; row-min over valid cols.
    // C/D layout (16x16x32): col = lane&15, row = q*4 + reg
    #pragma unroll
    for (int i = 0; i < 8; ++i) {
        #pragma unroll
        for (int rg = 0; rg < 4; ++rg) {
            const int row_l = wm * 128 + i * 16 + q * 4 + rg;
            const int lab = Ls[row_l];
            float m = POS_INF;
            #pragma unroll
            for (int j = 0; j < 4; ++j) {
                const int col = n0 + wn * 64 + j * 16 + l15;
                const float d = 1.0f - acc[i][j][rg];
                if (col == lab)
                    __hip_atomic_store(&pos[row0 + row_l], d,
                                       __ATOMIC_RELAXED, __HIP_MEMORY_SCOPE_AGENT);
                else if (col < C) m = fminf(m, d);
            }
            m = fminf(m, __shfl_xor(m, 1, 64));
            m = fminf(m, __shfl_xor(m, 2, 64));
            m = fminf(m, __shfl_xor(m, 4, 64));
            m = fminf(m, __shfl_xor(m, 8, 64));
            if (l15 == 0) sMinW[wn * BM + row_l] = m;
        }
    }
    __syncthreads();
    if (t < BM) {
        const float m = fminf(fminf(sMinW[t], sMinW[BM + t]),
                              fminf(sMinW[2 * BM + t], sMinW[3 * BM + t]));
        __hip_atomic_store(&partial[(size_t)nt * Bt + row0 + t], m,
                           __ATOMIC_RELAXED, __HIP_MEMORY_SCOPE_AGENT);
    }
    __syncthreads();  // drains vmcnt(0): all stores at coherence point

    // Completion counter: RELAXED on purpose (no buffer_inv/buffer_wbl2).
    if (t == 0) {
        __builtin_amdgcn_s_waitcnt(0);
        const int old = __hip_atomic_fetch_add(&cnt[rowblk], 1,
                                               __ATOMIC_RELAXED,
                                               __HIP_MEMORY_SCOPE_AGENT);
        *sLast = (old == NT - 1);
    }
    __syncthreads();
    if (!*sLast) return;

    float hng = 0.0f;
    if (t < BM) {
        const int r = row0 + t;
        float neg = POS_INF;
        for (int tt = 0; tt < NT; ++tt)
            neg = fminf(neg, __hip_atomic_load(&partial[(size_t)tt * Bt + r],
                                               __ATOMIC_RELAXED,
                                               __HIP_MEMORY_SCOPE_AGENT));
        const float p = __hip_atomic_load(&pos[r], __ATOMIC_RELAXED,
                                          __HIP_MEMORY_SCOPE_AGENT);
        hng = fmaxf(0.0f, p + margin - neg);
    }
    #pragma unroll
    for (int off = 32; off; off >>= 1) hng += __shfl_down(hng, off, 64);
    if (lane == 0) wsum[wave] = hng;
    __syncthreads();
    if (t == 0) {
        float s = 0.0f;
        #pragma unroll
        for (int w = 0; w < 8; ++w) s += wsum[w];
        atomicAdd(out, s * (1.0f / (float)Bt));
    }
}

extern "C" void kernel_launch(void* const* d_in, const int* in_sizes, int n_in,
                              void* d_out, int out_size, void* d_ws, size_t ws_size,
                              hipStream_t stream) {
    const float* x       = (const float*)d_in[0];
    const int*   labels  = (const int*)d_in[1];
    const float* centers = (const float*)d_in[2];
    float* out = (float*)d_out;

    const int Bt = in_sizes[1];           // 65536
    const int D  = in_sizes[0] / Bt;      // 512
    const int C  = in_sizes[2] / D;       // 1000
    const int NT = (C + BN - 1) / BN;     // 4
    const int CP = NT * BN;               // 1024
    const int NB = Bt / BM;               // 256 rowblocks

    char* ws = (char*)d_ws;
    unsigned short* cbf = (unsigned short*)ws;          // CP*D bf16 = 1 MB
    size_t off = (size_t)CP * D * 2;
    off = (off + 255) & ~(size_t)255;
    float* pos = (float*)(ws + off);      off += (size_t)Bt * 4;       // 256 KB
    float* partial = (float*)(ws + off);  off += (size_t)NT * Bt * 4;  // 1 MB
    int* cnt = (int*)(ws + off);          off += (size_t)NB * 4;
    off = (off + 255) & ~(size_t)255;
    unsigned short* xbf = (unsigned short*)(ws + off);   // 64 MB

    const size_t nx = (size_t)Bt * D;
    const int CB = CP / 4;                                // center blocks
    const int XB = (int)((nx / 8 + 255) / 256);           // convert blocks
    prep<<<CB + XB, 256, 0, stream>>>(centers, cbf, C, D, CP, CB, x, xbf, nx,
                                      cnt, NB, out);

    // 128 KB dynamic LDS needs the opt-in attribute (one-time, host-side,
    // not a stream op -> graph-capture safe).
    static bool lds_attr_set = false;
    if (!lds_attr_set) {
        hipFuncSetAttribute(reinterpret_cast<const void*>(gemm_fused),
                            hipFuncAttributeMaxDynamicSharedMemorySize,
                            2 * BUFSH * (int)sizeof(short));
        lds_attr_set = true;
    }
    gemm_fused<<<NB * NT, 512, 2 * BUFSH * sizeof(short), stream>>>(
        xbf, cbf, labels, pos, partial, cnt, Bt, C, D, NT, 1.0f, out);
}